// Round 5
// baseline (484.667 us; speedup 1.0000x reference)
//
#include <hip/hip_runtime.h>
#include <cstddef>

// ---------------------------------------------------------------------------
// GCN 2-layer forward. Round 8:
//  - GEMM rewritten with NO LDS and NO barriers: MFMA fragments are loaded
//    directly from global in fragment layout (A: 8 consecutive f32 per lane,
//    converted to bf16 hi/lo in regs via v_cvt_pk_bf16_f32; B: pre-transposed
//    [N][K] bf16, 8 consecutive elems per lane). LDS was a pure pass-through
//    (192 KB traffic per block per K-step > MFMA time) + 2 barriers; L2
//    absorbs the cross-wave re-reads (round-4 FETCH=103MB==|A| proved dedup
//    works even across y-blocks). OOB rows: load row clamped to M-1, store
//    guarded (garbage A row r only affects discarded D row r).
//  - Everything else unchanged (fp16 xw1 gather, CSR build, agg kernels).
// ---------------------------------------------------------------------------

typedef __attribute__((ext_vector_type(8))) short short8;
typedef __attribute__((ext_vector_type(4))) float f32x4;
typedef __attribute__((ext_vector_type(4))) _Float16 half4;

__device__ inline unsigned short f2bf(float f) {
    unsigned u = __float_as_uint(f);
    unsigned r = (u + 0x7fffu + ((u >> 16) & 1u)) >> 16;  // RNE
    return (unsigned short)r;
}
__device__ inline float bf2f(unsigned short h) {
    return __uint_as_float((unsigned)h << 16);
}

// packs bf16(a) into [15:0], bf16(b) into [31:16]
__device__ inline unsigned cvt_pk_bf16(float a, float b) {
    unsigned r;
    asm("v_cvt_pk_bf16_f32 %0, %1, %2" : "=v"(r) : "v"(a), "v"(b));
    return r;
}

__global__ void k_zero_i32(int* p, int n) {
    int i = blockIdx.x * blockDim.x + threadIdx.x;
    if (i < n) p[i] = 0;
}

__global__ void k_edge_hist(const int* __restrict__ dst, int* __restrict__ cnt, int E) {
    int e = blockIdx.x * blockDim.x + threadIdx.x;
    if (e < E) atomicAdd(&cnt[dst[e]], 1);
}

__global__ void k_dinv(const int* __restrict__ cnt, float* __restrict__ dinv, int N) {
    int i = blockIdx.x * blockDim.x + threadIdx.x;
    if (i < N) dinv[i] = rsqrtf((float)(cnt[i] + 1));  // +1 self-loop
}

__device__ inline int wave_incl_scan(int v) {
    const int lane = threadIdx.x & 63;
#pragma unroll
    for (int off = 1; off < 64; off <<= 1) {
        int u = __shfl_up(v, off);
        if (lane >= off) v += u;
    }
    return v;
}

__global__ __launch_bounds__(256) void k_chunk_sum(const int* __restrict__ cnt,
                                                   int* __restrict__ chunk_sum, int N) {
    __shared__ int wsum[4];
    const int i = blockIdx.x * 256 + threadIdx.x;
    int v = (i < N) ? cnt[i] : 0;
#pragma unroll
    for (int off = 32; off > 0; off >>= 1) v += __shfl_xor(v, off);
    if ((threadIdx.x & 63) == 0) wsum[threadIdx.x >> 6] = v;
    __syncthreads();
    if (threadIdx.x == 0)
        chunk_sum[blockIdx.x] = wsum[0] + wsum[1] + wsum[2] + wsum[3];
}

__global__ __launch_bounds__(256) void k_scan_chunks(const int* __restrict__ chunk_sum,
                                                     int* __restrict__ chunk_base, int CH) {
    __shared__ int wsum[4];
    const int t = threadIdx.x, lane = t & 63, wid = t >> 6;
    int v = (t < CH) ? chunk_sum[t] : 0;
    int incl = wave_incl_scan(v);
    if (lane == 63) wsum[wid] = incl;
    __syncthreads();
    int base = 0;
    for (int w = 0; w < 4; ++w) { int s = wsum[w]; if (w < wid) base += s; }
    if (t < CH) chunk_base[t] = base + incl - v;
}

__global__ __launch_bounds__(256) void k_expand(const int* __restrict__ cnt,
                                                const int* __restrict__ chunk_base,
                                                int* __restrict__ row_start,
                                                int* __restrict__ cursor, int N, int E) {
    __shared__ int wsum[4];
    const int t = threadIdx.x, lane = t & 63, wid = t >> 6;
    const int i = blockIdx.x * 256 + t;
    int v = (i < N) ? cnt[i] : 0;
    int incl = wave_incl_scan(v);
    if (lane == 63) wsum[wid] = incl;
    __syncthreads();
    int base = chunk_base[blockIdx.x];
    for (int w = 0; w < 4; ++w) { int s = wsum[w]; if (w < wid) base += s; }
    const int excl = base + incl - v;
    if (i < N) { row_start[i] = excl; cursor[i] = excl; }
    if (i == 0) row_start[N] = E;
}

__global__ void k_fill_csr(const int* __restrict__ src, const int* __restrict__ dst,
                           const float* __restrict__ dinv,
                           int* __restrict__ cursor, int* __restrict__ csr_src,
                           float* __restrict__ csr_w, int E) {
    int e = blockIdx.x * blockDim.x + threadIdx.x;
    if (e < E) {
        const int d = dst[e];
        const int s = src[e];
        const int p = atomicAdd(&cursor[d], 1);
        csr_src[p] = s;
        csr_w[p]   = dinv[s] * dinv[d];
    }
}

// W[K][N] f32  ->  Wt_hi/Wt_lo[N][K] bf16 (transposed + split)
__global__ void k_split_transpose(const float* __restrict__ W,
                                  unsigned short* __restrict__ Wh,
                                  unsigned short* __restrict__ Wl, int K, int N) {
    int i = blockIdx.x * blockDim.x + threadIdx.x;
    if (i < K * N) {
        const int k = i / N, n = i % N;
        const float v = W[i];
        const unsigned short h = f2bf(v);
        const unsigned short l = f2bf(v - bf2f(h));
        Wh[(size_t)n * K + k] = h;
        Wl[(size_t)n * K + k] = l;
    }
}

// C[M,N] = A[M,K] @ B[K,N], bf16x2-split MFMA, fragments direct from global.
// No LDS, no barriers. Block = 4 waves in 2x2; wave tile = 64 x (BN/2).
// A: f32 row-major. Bh/Bl: bf16 [N][K] (pre-transposed).
template<int BN, bool F16OUT>
__global__ __launch_bounds__(256) void k_gemm_reg(
    const float* __restrict__ A,
    const unsigned short* __restrict__ Bh,
    const unsigned short* __restrict__ Bl,
    void* __restrict__ Cv, int M, int N, int K) {
    constexpr int MF = 4;        // 4 x 16 rows per wave
    constexpr int NF = BN / 32;  // 16-col frags over wave's BN/2 cols

    const int t    = threadIdx.x;
    const int lane = t & 63;
    const int w    = t >> 6;
    const int wr   = w >> 1;      // 0..1
    const int wc   = w & 1;       // 0..1
    const int l15  = lane & 15;
    const int l4   = lane >> 4;
    const int bm   = blockIdx.x * 128;
    const int bn   = blockIdx.y * BN;

    f32x4 acc[MF][NF] = {};

    // Per-lane fragment base pointers (fixed; k advances via index).
    const float* ap[MF];
#pragma unroll
    for (int m = 0; m < MF; ++m) {
        int r = bm + wr * 64 + m * 16 + l15;
        if (r > M - 1) r = M - 1;             // clamp: garbage row discarded at store
        ap[m] = A + (size_t)r * K;
    }
    const unsigned short* bhp[NF];
    const unsigned short* blp[NF];
#pragma unroll
    for (int n = 0; n < NF; ++n) {
        const size_t off = (size_t)(bn + wc * (BN / 2) + n * 16 + l15) * K;
        bhp[n] = Bh + off;
        blp[n] = Bl + off;
    }

#pragma unroll 2
    for (int k0 = 0; k0 < K; k0 += 32) {
        const int kb = k0 + l4 * 8;
        short8 bh[NF], bl[NF];
#pragma unroll
        for (int n = 0; n < NF; ++n) {
            bh[n] = *(const short8*)(bhp[n] + kb);
            bl[n] = *(const short8*)(blp[n] + kb);
        }
#pragma unroll
        for (int m = 0; m < MF; ++m) {
            const float4 v0 = *(const float4*)(ap[m] + kb);
            const float4 v1 = *(const float4*)(ap[m] + kb + 4);
            const unsigned ph0 = cvt_pk_bf16(v0.x, v0.y);
            const unsigned ph1 = cvt_pk_bf16(v0.z, v0.w);
            const unsigned ph2 = cvt_pk_bf16(v1.x, v1.y);
            const unsigned ph3 = cvt_pk_bf16(v1.z, v1.w);
            const unsigned pl0 = cvt_pk_bf16(v0.x - __uint_as_float(ph0 << 16),
                                             v0.y - __uint_as_float(ph0 & 0xffff0000u));
            const unsigned pl1 = cvt_pk_bf16(v0.z - __uint_as_float(ph1 << 16),
                                             v0.w - __uint_as_float(ph1 & 0xffff0000u));
            const unsigned pl2 = cvt_pk_bf16(v1.x - __uint_as_float(ph2 << 16),
                                             v1.y - __uint_as_float(ph2 & 0xffff0000u));
            const unsigned pl3 = cvt_pk_bf16(v1.z - __uint_as_float(ph3 << 16),
                                             v1.w - __uint_as_float(ph3 & 0xffff0000u));
            uint4 hu = make_uint4(ph0, ph1, ph2, ph3);
            uint4 lu = make_uint4(pl0, pl1, pl2, pl3);
            const short8 ah = *(const short8*)&hu;
            const short8 al = *(const short8*)&lu;
#pragma unroll
            for (int n = 0; n < NF; ++n) {
                acc[m][n] = __builtin_amdgcn_mfma_f32_16x16x32_bf16(ah, bh[n], acc[m][n], 0, 0, 0);
                acc[m][n] = __builtin_amdgcn_mfma_f32_16x16x32_bf16(ah, bl[n], acc[m][n], 0, 0, 0);
                acc[m][n] = __builtin_amdgcn_mfma_f32_16x16x32_bf16(al, bh[n], acc[m][n], 0, 0, 0);
            }
        }
    }

    // ---- epilogue: C/D layout col = lane&15, row = (lane>>4)*4 + e ----
#pragma unroll
    for (int m = 0; m < MF; ++m) {
        const int row0 = bm + wr * 64 + m * 16 + l4 * 4;
#pragma unroll
        for (int e = 0; e < 4; ++e) {
            const int r = row0 + e;
            if (r < M) {
#pragma unroll
                for (int n = 0; n < NF; ++n) {
                    const size_t ci = (size_t)r * N + bn + wc * (BN / 2) + n * 16 + l15;
                    if constexpr (F16OUT)
                        ((_Float16*)Cv)[ci] = (_Float16)acc[m][n][e];
                    else
                        ((float*)Cv)[ci] = acc[m][n][e];
                }
            }
        }
    }
}

// Layer-1 aggregate: one wave per dst node, F=256, fp16 input (lane -> half4),
// f32 accumulate, unroll x4, f32 output.
__global__ __launch_bounds__(256) void k_agg256_relu(
    const int* __restrict__ row_start, const int* __restrict__ csr_src,
    const float* __restrict__ csr_w, const float* __restrict__ dinv,
    const _Float16* __restrict__ xw, const float* __restrict__ bias,
    float* __restrict__ out, int N) {
    const int node = blockIdx.x * 4 + (threadIdx.x >> 6);
    const int lane = threadIdx.x & 63;
    if (node >= N) return;

    const float dn  = dinv[node];
    const int   beg = row_start[node];
    const int   end = row_start[node + 1];

    const half4 hs = *(const half4*)(xw + (size_t)node * 256 + lane * 4);
    const float wself = dn * dn;
    float4 acc;
    acc.x = (float)hs.x * wself; acc.y = (float)hs.y * wself;
    acc.z = (float)hs.z * wself; acc.w = (float)hs.w * wself;

    int j = beg;
    const int end4 = beg + ((end - beg) & ~3);
    for (; j < end4; j += 4) {
        const int s0 = csr_src[j + 0], s1 = csr_src[j + 1];
        const int s2 = csr_src[j + 2], s3 = csr_src[j + 3];
        const float w0 = csr_w[j + 0], w1 = csr_w[j + 1];
        const float w2 = csr_w[j + 2], w3 = csr_w[j + 3];
        const half4 v0 = *(const half4*)(xw + (size_t)s0 * 256 + lane * 4);
        const half4 v1 = *(const half4*)(xw + (size_t)s1 * 256 + lane * 4);
        const half4 v2 = *(const half4*)(xw + (size_t)s2 * 256 + lane * 4);
        const half4 v3 = *(const half4*)(xw + (size_t)s3 * 256 + lane * 4);
        acc.x = fmaf((float)v0.x, w0, acc.x); acc.y = fmaf((float)v0.y, w0, acc.y);
        acc.z = fmaf((float)v0.z, w0, acc.z); acc.w = fmaf((float)v0.w, w0, acc.w);
        acc.x = fmaf((float)v1.x, w1, acc.x); acc.y = fmaf((float)v1.y, w1, acc.y);
        acc.z = fmaf((float)v1.z, w1, acc.z); acc.w = fmaf((float)v1.w, w1, acc.w);
        acc.x = fmaf((float)v2.x, w2, acc.x); acc.y = fmaf((float)v2.y, w2, acc.y);
        acc.z = fmaf((float)v2.z, w2, acc.z); acc.w = fmaf((float)v2.w, w2, acc.w);
        acc.x = fmaf((float)v3.x, w3, acc.x); acc.y = fmaf((float)v3.y, w3, acc.y);
        acc.z = fmaf((float)v3.z, w3, acc.z); acc.w = fmaf((float)v3.w, w3, acc.w);
    }
    for (; j < end; ++j) {
        const int   s = csr_src[j];
        const float w = csr_w[j];
        const half4 v = *(const half4*)(xw + (size_t)s * 256 + lane * 4);
        acc.x = fmaf((float)v.x, w, acc.x); acc.y = fmaf((float)v.y, w, acc.y);
        acc.z = fmaf((float)v.z, w, acc.z); acc.w = fmaf((float)v.w, w, acc.w);
    }

    const float4 b = ((const float4*)bias)[lane];
    acc.x = fmaxf(acc.x + b.x, 0.f);
    acc.y = fmaxf(acc.y + b.y, 0.f);
    acc.z = fmaxf(acc.z + b.z, 0.f);
    acc.w = fmaxf(acc.w + b.w, 0.f);
    *(float4*)(out + (size_t)node * 256 + lane * 4) = acc;
}

// Layer-2 aggregate + bias + softmax: one wave per dst node, F=64, unroll x4.
__global__ __launch_bounds__(256) void k_agg64_softmax(
    const int* __restrict__ row_start, const int* __restrict__ csr_src,
    const float* __restrict__ csr_w, const float* __restrict__ dinv,
    const float* __restrict__ xw, const float* __restrict__ bias,
    float* __restrict__ out, int N) {
    const int node = blockIdx.x * 4 + (threadIdx.x >> 6);
    const int lane = threadIdx.x & 63;
    if (node >= N) return;

    const float dn  = dinv[node];
    const int   beg = row_start[node];
    const int   end = row_start[node + 1];

    float acc = xw[(size_t)node * 64 + lane] * dn * dn;
    int j = beg;
    const int end4 = beg + ((end - beg) & ~3);
    for (; j < end4; j += 4) {
        const int s0 = csr_src[j + 0], s1 = csr_src[j + 1];
        const int s2 = csr_src[j + 2], s3 = csr_src[j + 3];
        const float w0 = csr_w[j + 0], w1 = csr_w[j + 1];
        const float w2 = csr_w[j + 2], w3 = csr_w[j + 3];
        const float v0 = xw[(size_t)s0 * 64 + lane];
        const float v1 = xw[(size_t)s1 * 64 + lane];
        const float v2 = xw[(size_t)s2 * 64 + lane];
        const float v3 = xw[(size_t)s3 * 64 + lane];
        acc = fmaf(v0, w0, acc);
        acc = fmaf(v1, w1, acc);
        acc = fmaf(v2, w2, acc);
        acc = fmaf(v3, w3, acc);
    }
    for (; j < end; ++j)
        acc = fmaf(xw[(size_t)csr_src[j] * 64 + lane], csr_w[j], acc);

    acc += bias[lane];

    float m = acc;
#pragma unroll
    for (int o = 32; o > 0; o >>= 1) m = fmaxf(m, __shfl_xor(m, o));
    const float e = expf(acc - m);
    float s = e;
#pragma unroll
    for (int o = 32; o > 0; o >>= 1) s += __shfl_xor(s, o);
    out[(size_t)node * 64 + lane] = e / s;
}

extern "C" void kernel_launch(void* const* d_in, const int* in_sizes, int n_in,
                              void* d_out, int out_size, void* d_ws, size_t ws_size,
                              hipStream_t stream) {
    const float* x  = (const float*)d_in[0];
    const int*   ei = (const int*)d_in[1];
    const float* W1 = (const float*)d_in[2];
    const float* b1 = (const float*)d_in[3];
    const float* W2 = (const float*)d_in[4];
    const float* b2 = (const float*)d_in[5];
    float* out = (float*)d_out;

    const int E = in_sizes[1] / 2;   // 800000
    const int N = out_size / 64;     // 50000
    const int* src = ei;
    const int* dst = ei + E;
    const int CH = (N + 255) / 256;  // 196 chunks

    char* ws = (char*)d_ws;
    size_t o = 0;
    auto alloc = [&](size_t bytes) {
        void* p = ws + o;
        o += (bytes + 255) & ~(size_t)255;
        return p;
    };
    int*   cnt        = (int*)alloc((size_t)N * 4);
    int*   chunk_sum  = (int*)alloc((size_t)256 * 4);
    int*   chunk_base = (int*)alloc((size_t)256 * 4);
    int*   row_start  = (int*)alloc((size_t)(N + 1) * 4);
    int*   cursor     = (int*)alloc((size_t)N * 4);
    int*   csr_src    = (int*)alloc((size_t)E * 4);
    float* csr_w      = (float*)alloc((size_t)E * 4);
    float* dinv       = (float*)alloc((size_t)N * 4);
    _Float16* xw1     = (_Float16*)alloc((size_t)N * 256 * 2);
    float* h1         = (float*)alloc((size_t)N * 256 * 4);
    float* xw2        = (float*)alloc((size_t)N * 64 * 4);
    unsigned short* wt1h = (unsigned short*)alloc((size_t)256 * 512 * 2);
    unsigned short* wt1l = (unsigned short*)alloc((size_t)256 * 512 * 2);
    unsigned short* wt2h = (unsigned short*)alloc((size_t)64 * 256 * 2);
    unsigned short* wt2l = (unsigned short*)alloc((size_t)64 * 256 * 2);
    (void)ws_size; (void)n_in;

    // ---- CSR build + dinv + weight transpose/split ----
    k_zero_i32<<<(N + 255) / 256, 256, 0, stream>>>(cnt, N);
    k_edge_hist<<<(E + 255) / 256, 256, 0, stream>>>(dst, cnt, E);
    k_dinv<<<(N + 255) / 256, 256, 0, stream>>>(cnt, dinv, N);
    k_chunk_sum<<<CH, 256, 0, stream>>>(cnt, chunk_sum, N);
    k_scan_chunks<<<1, 256, 0, stream>>>(chunk_sum, chunk_base, CH);
    k_expand<<<CH, 256, 0, stream>>>(cnt, chunk_base, row_start, cursor, N, E);
    k_fill_csr<<<(E + 255) / 256, 256, 0, stream>>>(src, dst, dinv, cursor, csr_src, csr_w, E);
    k_split_transpose<<<(512 * 256 + 255) / 256, 256, 0, stream>>>(W1, wt1h, wt1l, 512, 256);
    k_split_transpose<<<(256 * 64 + 255) / 256, 256, 0, stream>>>(W2, wt2h, wt2l, 256, 64);

    // ---- layer 1: xw1 = x @ W1 (reg MFMA, fp16 out), aggregate+ReLU ----
    dim3 g1((N + 127) / 128, 2);
    k_gemm_reg<128, true><<<g1, 256, 0, stream>>>(x, wt1h, wt1l, xw1, N, 256, 512);
    k_agg256_relu<<<(N + 3) / 4, 256, 0, stream>>>(row_start, csr_src, csr_w, dinv, xw1, b1, h1, N);

    // ---- layer 2: xw2 = h1 @ W2 (reg MFMA), aggregate+softmax ----
    dim3 g2((N + 127) / 128, 1);
    k_gemm_reg<64, false><<<g2, 256, 0, stream>>>(h1, wt2h, wt2l, xw2, N, 64, 256);
    k_agg64_softmax<<<(N + 3) / 4, 256, 0, stream>>>(row_start, csr_src, csr_w, dinv, xw2, b2, out, N);
}

// Round 6
// 417.074 us; speedup vs baseline: 1.1621x; 1.1621x over previous
//
#include <hip/hip_runtime.h>
#include <cstddef>

// ---------------------------------------------------------------------------
// GCN 2-layer forward. Round 9:
//  - Round 8 (no-LDS) post-mortem: scattered 16-row fragment loads killed
//    VMEM issue economics (all pipes ~11%). REVERTED to round-7 structure.
//  - Round 7 was LDS-BW-bound (192 KB/block/K-tile vs ~920 cyc MFMA).
//    Now B bypasses LDS via PRE-PACKED fragment-major layout
//    [nf][K/32][lane][8]: one coalesced dwordx4 per B fragment, L2-resident
//    (<=1 MB). A keeps reg-pipelined coalesced staging through LDS (32 KB).
//    LDS traffic per K-tile: 192 KB -> 96 KB.
//  - Everything else unchanged (fp16 xw1 gather, CSR build, agg kernels).
// ---------------------------------------------------------------------------

typedef __attribute__((ext_vector_type(8))) short short8;
typedef __attribute__((ext_vector_type(4))) float f32x4;
typedef __attribute__((ext_vector_type(4))) _Float16 half4;

__device__ inline unsigned short f2bf(float f) {
    unsigned u = __float_as_uint(f);
    unsigned r = (u + 0x7fffu + ((u >> 16) & 1u)) >> 16;  // RNE
    return (unsigned short)r;
}
__device__ inline float bf2f(unsigned short h) {
    return __uint_as_float((unsigned)h << 16);
}

// packs bf16(a) into [15:0], bf16(b) into [31:16]
__device__ inline unsigned cvt_pk_bf16(float a, float b) {
    unsigned r;
    asm("v_cvt_pk_bf16_f32 %0, %1, %2" : "=v"(r) : "v"(a), "v"(b));
    return r;
}

__global__ void k_zero_i32(int* p, int n) {
    int i = blockIdx.x * blockDim.x + threadIdx.x;
    if (i < n) p[i] = 0;
}

__global__ void k_edge_hist(const int* __restrict__ dst, int* __restrict__ cnt, int E) {
    int e = blockIdx.x * blockDim.x + threadIdx.x;
    if (e < E) atomicAdd(&cnt[dst[e]], 1);
}

__global__ void k_dinv(const int* __restrict__ cnt, float* __restrict__ dinv, int N) {
    int i = blockIdx.x * blockDim.x + threadIdx.x;
    if (i < N) dinv[i] = rsqrtf((float)(cnt[i] + 1));  // +1 self-loop
}

__device__ inline int wave_incl_scan(int v) {
    const int lane = threadIdx.x & 63;
#pragma unroll
    for (int off = 1; off < 64; off <<= 1) {
        int u = __shfl_up(v, off);
        if (lane >= off) v += u;
    }
    return v;
}

__global__ __launch_bounds__(256) void k_chunk_sum(const int* __restrict__ cnt,
                                                   int* __restrict__ chunk_sum, int N) {
    __shared__ int wsum[4];
    const int i = blockIdx.x * 256 + threadIdx.x;
    int v = (i < N) ? cnt[i] : 0;
#pragma unroll
    for (int off = 32; off > 0; off >>= 1) v += __shfl_xor(v, off);
    if ((threadIdx.x & 63) == 0) wsum[threadIdx.x >> 6] = v;
    __syncthreads();
    if (threadIdx.x == 0)
        chunk_sum[blockIdx.x] = wsum[0] + wsum[1] + wsum[2] + wsum[3];
}

__global__ __launch_bounds__(256) void k_scan_chunks(const int* __restrict__ chunk_sum,
                                                     int* __restrict__ chunk_base, int CH) {
    __shared__ int wsum[4];
    const int t = threadIdx.x, lane = t & 63, wid = t >> 6;
    int v = (t < CH) ? chunk_sum[t] : 0;
    int incl = wave_incl_scan(v);
    if (lane == 63) wsum[wid] = incl;
    __syncthreads();
    int base = 0;
    for (int w = 0; w < 4; ++w) { int s = wsum[w]; if (w < wid) base += s; }
    if (t < CH) chunk_base[t] = base + incl - v;
}

__global__ __launch_bounds__(256) void k_expand(const int* __restrict__ cnt,
                                                const int* __restrict__ chunk_base,
                                                int* __restrict__ row_start,
                                                int* __restrict__ cursor, int N, int E) {
    __shared__ int wsum[4];
    const int t = threadIdx.x, lane = t & 63, wid = t >> 6;
    const int i = blockIdx.x * 256 + t;
    int v = (i < N) ? cnt[i] : 0;
    int incl = wave_incl_scan(v);
    if (lane == 63) wsum[wid] = incl;
    __syncthreads();
    int base = chunk_base[blockIdx.x];
    for (int w = 0; w < 4; ++w) { int s = wsum[w]; if (w < wid) base += s; }
    const int excl = base + incl - v;
    if (i < N) { row_start[i] = excl; cursor[i] = excl; }
    if (i == 0) row_start[N] = E;
}

__global__ void k_fill_csr(const int* __restrict__ src, const int* __restrict__ dst,
                           const float* __restrict__ dinv,
                           int* __restrict__ cursor, int* __restrict__ csr_src,
                           float* __restrict__ csr_w, int E) {
    int e = blockIdx.x * blockDim.x + threadIdx.x;
    if (e < E) {
        const int d = dst[e];
        const int s = src[e];
        const int p = atomicAdd(&cursor[d], 1);
        csr_src[p] = s;
        csr_w[p]   = dinv[s] * dinv[d];
    }
}

// W[K][N] f32 -> fragment-major packed bf16 hi/lo:
// P[nf][K/32][lane][8] where lane = (k>>3 & 3)*16 + (n&15), elem j = k&7.
// A wave's B-fragment load becomes lane-contiguous (fully coalesced 16B/lane).
__global__ void k_pack_b(const float* __restrict__ W,
                         unsigned short* __restrict__ Ph,
                         unsigned short* __restrict__ Pl, int K, int N) {
    int i = blockIdx.x * blockDim.x + threadIdx.x;
    if (i < K * N) {
        const int k = i / N, n = i % N;
        const float v = W[i];
        const unsigned short h = f2bf(v);
        const unsigned short l = f2bf(v - bf2f(h));
        const int nf = n >> 4, l15 = n & 15;
        const int kb = k >> 5, l4 = (k >> 3) & 3, j = k & 7;
        const size_t dst = ((((size_t)nf * (K >> 5) + kb) * 64) + l4 * 16 + l15) * 8 + j;
        Ph[dst] = h;
        Pl[dst] = l;
    }
}

// C[M,N] = A[M,K] @ B[K,N], bf16x2-split MFMA.
// A: f32 row-major, reg-pipelined + staged to LDS (cvt_pk split, swizzled).
// B: packed fragment-major bf16 hi/lo (k_pack_b), loaded direct from global.
// 256 threads = 4 waves 2x2; wave tile = 64 x (BN/2); BK = 64.
template<int BN, bool F16OUT>
__global__ __launch_bounds__(256, 2) void k_gemm_mfma(
    const float* __restrict__ A,
    const unsigned short* __restrict__ Bph,
    const unsigned short* __restrict__ Bpl,
    void* __restrict__ Cv, int M, int N, int K) {
    constexpr int BM  = 128, BK = 64;
    constexpr int MF  = 4;                    // 4 x 16 rows per wave
    constexpr int NF  = BN / 32;              // frags over wave's BN/2 cols
    constexpr int NA4 = BM * BK / 4 / 256;    // 8 float4 per thread (A tile)

    __shared__ unsigned short Ash[BM * BK];
    __shared__ unsigned short Asl[BM * BK];

    const int t    = threadIdx.x;
    const int lane = t & 63;
    const int w    = t >> 6;
    const int wr   = w >> 1;      // 0..1
    const int wc   = w & 1;       // 0..1
    const int l15  = lane & 15;
    const int l4   = lane >> 4;
    const int bm   = blockIdx.x * BM;
    const int bn   = blockIdx.y * BN;

    const int K32     = K >> 5;
    const int nf_base = (bn + wc * (BN / 2)) >> 4;

    f32x4 acc[MF][NF] = {};

    float4 araw[NA4];   // raw A tile one K-step ahead

    auto issue_loads = [&](int k0) {
#pragma unroll
        for (int i = 0; i < NA4; ++i) {
            const int idx = t + i * 256;
            const int ar  = idx >> 4;         // 0..BM-1
            const int ac  = (idx & 15) * 4;   // 0..60
            const int am  = bm + ar;
            araw[i] = (am < M) ? *(const float4*)(A + (size_t)am * K + k0 + ac)
                               : make_float4(0.f, 0.f, 0.f, 0.f);
        }
    };

    auto stage_to_lds = [&]() {
#pragma unroll
        for (int i = 0; i < NA4; ++i) {
            const int idx = t + i * 256;
            const int ar  = idx >> 4;
            const int ac  = (idx & 15) * 4;
            const float4 v = araw[i];
            const unsigned ph0 = cvt_pk_bf16(v.x, v.y);
            const unsigned ph1 = cvt_pk_bf16(v.z, v.w);
            const float h0 = __uint_as_float(ph0 << 16);
            const float h1 = __uint_as_float(ph0 & 0xffff0000u);
            const float h2 = __uint_as_float(ph1 << 16);
            const float h3 = __uint_as_float(ph1 & 0xffff0000u);
            const unsigned pl0 = cvt_pk_bf16(v.x - h0, v.y - h1);
            const unsigned pl1 = cvt_pk_bf16(v.z - h2, v.w - h3);
            const int si = (ar * BK + ac) ^ ((ar & 7) << 3);
            *(uint2*)&Ash[si] = make_uint2(ph0, ph1);
            *(uint2*)&Asl[si] = make_uint2(pl0, pl1);
        }
    };

    const int NT = K / BK;
    issue_loads(0);
    for (int ts = 0; ts < NT; ++ts) {
        stage_to_lds();                              // consumes raw tile ts
        if (ts + 1 < NT) issue_loads((ts + 1) * BK); // in flight across MFMA
        __syncthreads();

        const int k0 = ts * BK;
#pragma unroll
        for (int kk = 0; kk < BK; kk += 32) {
            const int kb   = kk + l4 * 8;        // A LDS k-offset
            const int kb32 = (k0 + kk) >> 5;     // packed-B K/32 index
            short8 bh[NF], bl[NF];
#pragma unroll
            for (int n = 0; n < NF; ++n) {
                const size_t boff =
                    (((size_t)(nf_base + n) * K32 + kb32) * 64 + lane) * 8;
                bh[n] = *(const short8*)(Bph + boff);
                bl[n] = *(const short8*)(Bpl + boff);
            }
#pragma unroll
            for (int m = 0; m < MF; ++m) {
                const int row = wr * 64 + m * 16 + l15;
                const int si  = (row * BK + kb) ^ ((row & 7) << 3);
                const short8 ah = *(const short8*)&Ash[si];
                const short8 al = *(const short8*)&Asl[si];
#pragma unroll
                for (int n = 0; n < NF; ++n) {
                    acc[m][n] = __builtin_amdgcn_mfma_f32_16x16x32_bf16(ah, bh[n], acc[m][n], 0, 0, 0);
                    acc[m][n] = __builtin_amdgcn_mfma_f32_16x16x32_bf16(ah, bl[n], acc[m][n], 0, 0, 0);
                    acc[m][n] = __builtin_amdgcn_mfma_f32_16x16x32_bf16(al, bh[n], acc[m][n], 0, 0, 0);
                }
            }
        }
        __syncthreads();
    }

    // ---- epilogue: C/D layout col = lane&15, row = (lane>>4)*4 + e ----
#pragma unroll
    for (int m = 0; m < MF; ++m) {
        const int row0 = bm + wr * 64 + m * 16 + l4 * 4;
#pragma unroll
        for (int e = 0; e < 4; ++e) {
            const int r = row0 + e;
            if (r < M) {
#pragma unroll
                for (int n = 0; n < NF; ++n) {
                    const size_t ci = (size_t)r * N + bn + wc * (BN / 2) + n * 16 + l15;
                    if constexpr (F16OUT)
                        ((_Float16*)Cv)[ci] = (_Float16)acc[m][n][e];
                    else
                        ((float*)Cv)[ci] = acc[m][n][e];
                }
            }
        }
    }
}

// Layer-1 aggregate: one wave per dst node, F=256, fp16 input (lane -> half4),
// f32 accumulate, unroll x4, f32 output.
__global__ __launch_bounds__(256) void k_agg256_relu(
    const int* __restrict__ row_start, const int* __restrict__ csr_src,
    const float* __restrict__ csr_w, const float* __restrict__ dinv,
    const _Float16* __restrict__ xw, const float* __restrict__ bias,
    float* __restrict__ out, int N) {
    const int node = blockIdx.x * 4 + (threadIdx.x >> 6);
    const int lane = threadIdx.x & 63;
    if (node >= N) return;

    const float dn  = dinv[node];
    const int   beg = row_start[node];
    const int   end = row_start[node + 1];

    const half4 hs = *(const half4*)(xw + (size_t)node * 256 + lane * 4);
    const float wself = dn * dn;
    float4 acc;
    acc.x = (float)hs.x * wself; acc.y = (float)hs.y * wself;
    acc.z = (float)hs.z * wself; acc.w = (float)hs.w * wself;

    int j = beg;
    const int end4 = beg + ((end - beg) & ~3);
    for (; j < end4; j += 4) {
        const int s0 = csr_src[j + 0], s1 = csr_src[j + 1];
        const int s2 = csr_src[j + 2], s3 = csr_src[j + 3];
        const float w0 = csr_w[j + 0], w1 = csr_w[j + 1];
        const float w2 = csr_w[j + 2], w3 = csr_w[j + 3];
        const half4 v0 = *(const half4*)(xw + (size_t)s0 * 256 + lane * 4);
        const half4 v1 = *(const half4*)(xw + (size_t)s1 * 256 + lane * 4);
        const half4 v2 = *(const half4*)(xw + (size_t)s2 * 256 + lane * 4);
        const half4 v3 = *(const half4*)(xw + (size_t)s3 * 256 + lane * 4);
        acc.x = fmaf((float)v0.x, w0, acc.x); acc.y = fmaf((float)v0.y, w0, acc.y);
        acc.z = fmaf((float)v0.z, w0, acc.z); acc.w = fmaf((float)v0.w, w0, acc.w);
        acc.x = fmaf((float)v1.x, w1, acc.x); acc.y = fmaf((float)v1.y, w1, acc.y);
        acc.z = fmaf((float)v1.z, w1, acc.z); acc.w = fmaf((float)v1.w, w1, acc.w);
        acc.x = fmaf((float)v2.x, w2, acc.x); acc.y = fmaf((float)v2.y, w2, acc.y);
        acc.z = fmaf((float)v2.z, w2, acc.z); acc.w = fmaf((float)v2.w, w2, acc.w);
        acc.x = fmaf((float)v3.x, w3, acc.x); acc.y = fmaf((float)v3.y, w3, acc.y);
        acc.z = fmaf((float)v3.z, w3, acc.z); acc.w = fmaf((float)v3.w, w3, acc.w);
    }
    for (; j < end; ++j) {
        const int   s = csr_src[j];
        const float w = csr_w[j];
        const half4 v = *(const half4*)(xw + (size_t)s * 256 + lane * 4);
        acc.x = fmaf((float)v.x, w, acc.x); acc.y = fmaf((float)v.y, w, acc.y);
        acc.z = fmaf((float)v.z, w, acc.z); acc.w = fmaf((float)v.w, w, acc.w);
    }

    const float4 b = ((const float4*)bias)[lane];
    acc.x = fmaxf(acc.x + b.x, 0.f);
    acc.y = fmaxf(acc.y + b.y, 0.f);
    acc.z = fmaxf(acc.z + b.z, 0.f);
    acc.w = fmaxf(acc.w + b.w, 0.f);
    *(float4*)(out + (size_t)node * 256 + lane * 4) = acc;
}

// Layer-2 aggregate + bias + softmax: one wave per dst node, F=64, unroll x4.
__global__ __launch_bounds__(256) void k_agg64_softmax(
    const int* __restrict__ row_start, const int* __restrict__ csr_src,
    const float* __restrict__ csr_w, const float* __restrict__ dinv,
    const float* __restrict__ xw, const float* __restrict__ bias,
    float* __restrict__ out, int N) {
    const int node = blockIdx.x * 4 + (threadIdx.x >> 6);
    const int lane = threadIdx.x & 63;
    if (node >= N) return;

    const float dn  = dinv[node];
    const int   beg = row_start[node];
    const int   end = row_start[node + 1];

    float acc = xw[(size_t)node * 64 + lane] * dn * dn;
    int j = beg;
    const int end4 = beg + ((end - beg) & ~3);
    for (; j < end4; j += 4) {
        const int s0 = csr_src[j + 0], s1 = csr_src[j + 1];
        const int s2 = csr_src[j + 2], s3 = csr_src[j + 3];
        const float w0 = csr_w[j + 0], w1 = csr_w[j + 1];
        const float w2 = csr_w[j + 2], w3 = csr_w[j + 3];
        const float v0 = xw[(size_t)s0 * 64 + lane];
        const float v1 = xw[(size_t)s1 * 64 + lane];
        const float v2 = xw[(size_t)s2 * 64 + lane];
        const float v3 = xw[(size_t)s3 * 64 + lane];
        acc = fmaf(v0, w0, acc);
        acc = fmaf(v1, w1, acc);
        acc = fmaf(v2, w2, acc);
        acc = fmaf(v3, w3, acc);
    }
    for (; j < end; ++j)
        acc = fmaf(xw[(size_t)csr_src[j] * 64 + lane], csr_w[j], acc);

    acc += bias[lane];

    float m = acc;
#pragma unroll
    for (int o = 32; o > 0; o >>= 1) m = fmaxf(m, __shfl_xor(m, o));
    const float e = expf(acc - m);
    float s = e;
#pragma unroll
    for (int o = 32; o > 0; o >>= 1) s += __shfl_xor(s, o);
    out[(size_t)node * 64 + lane] = e / s;
}

extern "C" void kernel_launch(void* const* d_in, const int* in_sizes, int n_in,
                              void* d_out, int out_size, void* d_ws, size_t ws_size,
                              hipStream_t stream) {
    const float* x  = (const float*)d_in[0];
    const int*   ei = (const int*)d_in[1];
    const float* W1 = (const float*)d_in[2];
    const float* b1 = (const float*)d_in[3];
    const float* W2 = (const float*)d_in[4];
    const float* b2 = (const float*)d_in[5];
    float* out = (float*)d_out;

    const int E = in_sizes[1] / 2;   // 800000
    const int N = out_size / 64;     // 50000
    const int* src = ei;
    const int* dst = ei + E;
    const int CH = (N + 255) / 256;  // 196 chunks

    char* ws = (char*)d_ws;
    size_t o = 0;
    auto alloc = [&](size_t bytes) {
        void* p = ws + o;
        o += (bytes + 255) & ~(size_t)255;
        return p;
    };
    int*   cnt        = (int*)alloc((size_t)N * 4);
    int*   chunk_sum  = (int*)alloc((size_t)256 * 4);
    int*   chunk_base = (int*)alloc((size_t)256 * 4);
    int*   row_start  = (int*)alloc((size_t)(N + 1) * 4);
    int*   cursor     = (int*)alloc((size_t)N * 4);
    int*   csr_src    = (int*)alloc((size_t)E * 4);
    float* csr_w      = (float*)alloc((size_t)E * 4);
    float* dinv       = (float*)alloc((size_t)N * 4);
    _Float16* xw1     = (_Float16*)alloc((size_t)N * 256 * 2);
    float* h1         = (float*)alloc((size_t)N * 256 * 4);
    float* xw2        = (float*)alloc((size_t)N * 64 * 4);
    unsigned short* wt1h = (unsigned short*)alloc((size_t)256 * 512 * 2);
    unsigned short* wt1l = (unsigned short*)alloc((size_t)256 * 512 * 2);
    unsigned short* wt2h = (unsigned short*)alloc((size_t)64 * 256 * 2);
    unsigned short* wt2l = (unsigned short*)alloc((size_t)64 * 256 * 2);
    (void)ws_size; (void)n_in;

    // ---- CSR build + dinv + weight pack/split ----
    k_zero_i32<<<(N + 255) / 256, 256, 0, stream>>>(cnt, N);
    k_edge_hist<<<(E + 255) / 256, 256, 0, stream>>>(dst, cnt, E);
    k_dinv<<<(N + 255) / 256, 256, 0, stream>>>(cnt, dinv, N);
    k_chunk_sum<<<CH, 256, 0, stream>>>(cnt, chunk_sum, N);
    k_scan_chunks<<<1, 256, 0, stream>>>(chunk_sum, chunk_base, CH);
    k_expand<<<CH, 256, 0, stream>>>(cnt, chunk_base, row_start, cursor, N, E);
    k_fill_csr<<<(E + 255) / 256, 256, 0, stream>>>(src, dst, dinv, cursor, csr_src, csr_w, E);
    k_pack_b<<<(512 * 256 + 255) / 256, 256, 0, stream>>>(W1, wt1h, wt1l, 512, 256);
    k_pack_b<<<(256 * 64 + 255) / 256, 256, 0, stream>>>(W2, wt2h, wt2l, 256, 64);

    // ---- layer 1: xw1 = x @ W1 (MFMA split, fp16 out), aggregate+ReLU ----
    dim3 g1((N + 127) / 128, 2);
    k_gemm_mfma<128, true><<<g1, 256, 0, stream>>>(x, wt1h, wt1l, xw1, N, 256, 512);
    k_agg256_relu<<<(N + 3) / 4, 256, 0, stream>>>(row_start, csr_src, csr_w, dinv, xw1, b1, h1, N);

    // ---- layer 2: xw2 = h1 @ W2 (MFMA split), aggregate+softmax ----
    dim3 g2((N + 127) / 128, 1);
    k_gemm_mfma<64, false><<<g2, 256, 0, stream>>>(h1, wt2h, wt2l, xw2, N, 64, 256);
    k_agg64_softmax<<<(N + 3) / 4, 256, 0, stream>>>(row_start, csr_src, csr_w, dinv, xw2, b2, out, N);
}